// Round 9
// baseline (40.758 us; speedup 1.0000x reference)
//
#include <hip/hip_runtime.h>

// out[k][j] = max( x1[k][j], max_i( W[i][j]*x0[k][i] + B[i][j] + C_norm[i][j] ) )
// N=4096, D=256, f32 in/out. pk-f16 math (absmax 0.031 < 0.101 validated).
//
// DIAGNOSTIC ROUND: REPS=3 replicates stage+compute (idempotent max) to push
// the kernel past the 40us rocprof visibility threshold. Geometry: 512 blocks
// x 512 thr (2 blk/CU, 4 waves/SIMD). Tile 64k x 32j, 16-way i-split (16 i's
// per thread), per-thread 8k x 8j. X tile XOR-swizzled by k-group (store AND
// read) -> X reads 2-way max. Regs lean. LDS 64KB. Tree-merge + epilogue.

typedef _Float16 h16;
typedef h16 h2  __attribute__((ext_vector_type(2)));
typedef h16 h8v __attribute__((ext_vector_type(8)));
typedef float f32x4 __attribute__((ext_vector_type(4)));

constexpr int Dk = 256;
constexpr int REPS = 3;

__global__ __launch_bounds__(512, 4)
void mp_kernel(const float* __restrict__ x0, const float* __restrict__ x1,
               const float* __restrict__ Cn, const float* __restrict__ W,
               const float* __restrict__ Bm, float* __restrict__ out) {
  __shared__ __align__(16) h16 smem[32768];   // 64 KB
  h16* Xl = smem;            // [64 k][256 i], col ^= (k>>3)*8   32KB
  h16* Wl = smem + 16384;    // [256 i][32 j]                    16KB
  h16* Al = smem + 24576;    // [256 i][32 j]                    16KB

  const int tid = threadIdx.x;
  const int s  = tid >> 5;         // i-slice 0..15 (16 i's each)
  const int t5 = tid & 31;
  const int tk = t5 >> 2;          // k-group 0..7 (8 k's)
  const int tj = t5 & 3;           // j-group 0..3 (8 j's)
  const int k0 = (int)(blockIdx.x >> 3) * 64;
  const int j0 = (int)(blockIdx.x & 7) * 32;

  h2 acc[8][4];
#pragma unroll
  for (int kk = 0; kk < 8; ++kk)
#pragma unroll
    for (int p = 0; p < 4; ++p)
      acc[kk][p] = h2{(h16)(-60000.0f), (h16)(-60000.0f)};

  for (int rep = 0; rep < REPS; ++rep) {
    // opaque (runtime-zero) offset: defeats cross-rep global-load CSE
    const int zz = (int)blockIdx.y * rep;
    const float* xp = x0 + zz;
    const float* wp = W  + zz;
    const float* bp = Bm + zz;
    const float* cp = Cn + zz;

    if (rep) __syncthreads();   // prior rep's LDS reads must finish

    // ---- stage X tile (64k x 256i), swizzled store ----
#pragma unroll
    for (int c = 0; c < 4; ++c) {
      const int idx = c * 512 + tid;          // 2048 chunks
      const int row = idx >> 5;               // k-row 0..63
      const int ic8 = (idx & 31) * 8;         // i chunk base
      const f32x4 v0 = *reinterpret_cast<const f32x4*>(&xp[(k0 + row) * Dk + ic8]);
      const f32x4 v1 = *reinterpret_cast<const f32x4*>(&xp[(k0 + row) * Dk + ic8 + 4]);
      h8v h;
#pragma unroll
      for (int u = 0; u < 4; ++u) { h[u] = (h16)v0[u]; h[u + 4] = (h16)v1[u]; }
      const int sw = ic8 ^ ((row >> 3) * 8);
      *reinterpret_cast<h8v*>(&Xl[row * 256 + sw]) = h;
    }
    // ---- stage W and A = B + C (256i x 32j each) ----
#pragma unroll
    for (int c = 0; c < 2; ++c) {
      const int idx = c * 512 + tid;          // 1024 chunks
      const int row = idx >> 2;               // i 0..255
      const int jc8 = (idx & 3) * 8;
      const int g = row * Dk + j0 + jc8;
      const f32x4 w0 = *reinterpret_cast<const f32x4*>(&wp[g]);
      const f32x4 w1 = *reinterpret_cast<const f32x4*>(&wp[g + 4]);
      const f32x4 b0 = *reinterpret_cast<const f32x4*>(&bp[g]);
      const f32x4 b1 = *reinterpret_cast<const f32x4*>(&bp[g + 4]);
      const f32x4 c0 = *reinterpret_cast<const f32x4*>(&cp[g]);
      const f32x4 c1 = *reinterpret_cast<const f32x4*>(&cp[g + 4]);
      const f32x4 a0 = b0 + c0, a1 = b1 + c1;
      h8v hw, ha;
#pragma unroll
      for (int u = 0; u < 4; ++u) {
        hw[u] = (h16)w0[u]; hw[u + 4] = (h16)w1[u];
        ha[u] = (h16)a0[u]; ha[u + 4] = (h16)a1[u];
      }
      *reinterpret_cast<h8v*>(&Wl[row * 32 + jc8]) = hw;
      *reinterpret_cast<h8v*>(&Al[row * 32 + jc8]) = ha;
    }
    __syncthreads();

    // ---- compute: 16 i's, two 8-i halves; xr cached across U ----
#define USTEP(U) {                                                              \
    const int ii = i0 + (U);                                                    \
    const h8v wv = *reinterpret_cast<const h8v*>(&Wl[ii * 32 + tj * 8]);        \
    const h8v av = *reinterpret_cast<const h8v*>(&Al[ii * 32 + tj * 8]);        \
    const h2 w0 = __builtin_shufflevector(wv, wv, 0, 1);                        \
    const h2 w1 = __builtin_shufflevector(wv, wv, 2, 3);                        \
    const h2 w2 = __builtin_shufflevector(wv, wv, 4, 5);                        \
    const h2 w3 = __builtin_shufflevector(wv, wv, 6, 7);                        \
    const h2 a0 = __builtin_shufflevector(av, av, 0, 1);                        \
    const h2 a1 = __builtin_shufflevector(av, av, 2, 3);                        \
    const h2 a2 = __builtin_shufflevector(av, av, 4, 5);                        \
    const h2 a3 = __builtin_shufflevector(av, av, 6, 7);                        \
    _Pragma("unroll")                                                           \
    for (int kk = 0; kk < 8; ++kk) {                                            \
      const h2 xb = __builtin_shufflevector(xr[kk], xr[kk], (U), (U));          \
      acc[kk][0] = __builtin_elementwise_max(acc[kk][0], __builtin_elementwise_fma(w0, xb, a0)); \
      acc[kk][1] = __builtin_elementwise_max(acc[kk][1], __builtin_elementwise_fma(w1, xb, a1)); \
      acc[kk][2] = __builtin_elementwise_max(acc[kk][2], __builtin_elementwise_fma(w2, xb, a2)); \
      acc[kk][3] = __builtin_elementwise_max(acc[kk][3], __builtin_elementwise_fma(w3, xb, a3)); \
    }                                                                           \
  }

#pragma unroll
    for (int hh = 0; hh < 2; ++hh) {
      const int i0 = s * 16 + hh * 8;
      h8v xr[8];
#pragma unroll
      for (int kk = 0; kk < 8; ++kk) {
        const int row = tk * 8 + kk;
        xr[kk] = *reinterpret_cast<const h8v*>(
            &Xl[row * 256 + (i0 ^ ((row >> 3) * 8))]);
      }
      USTEP(0) USTEP(1) USTEP(2) USTEP(3) USTEP(4) USTEP(5) USTEP(6) USTEP(7)
    }
#undef USTEP
  }
  __syncthreads();   // LDS reuse as merge scratch

  // ---- tree merge: 16 i-slices -> 1 ----
  uint4* mrg = reinterpret_cast<uint4*>(smem);
  auto wslot = [&](int slot) {
#pragma unroll
    for (int c = 0; c < 8; ++c) {
      uint4 u;
      u.x = __builtin_bit_cast(unsigned int, acc[c][0]);
      u.y = __builtin_bit_cast(unsigned int, acc[c][1]);
      u.z = __builtin_bit_cast(unsigned int, acc[c][2]);
      u.w = __builtin_bit_cast(unsigned int, acc[c][3]);
      mrg[(slot * 32 + t5) * 8 + (c ^ (t5 & 7))] = u;
    }
  };
  auto rmerge = [&](int slot) {
#pragma unroll
    for (int c = 0; c < 8; ++c) {
      const uint4 u = mrg[(slot * 32 + t5) * 8 + (c ^ (t5 & 7))];
      acc[c][0] = __builtin_elementwise_max(acc[c][0], __builtin_bit_cast(h2, u.x));
      acc[c][1] = __builtin_elementwise_max(acc[c][1], __builtin_bit_cast(h2, u.y));
      acc[c][2] = __builtin_elementwise_max(acc[c][2], __builtin_bit_cast(h2, u.z));
      acc[c][3] = __builtin_elementwise_max(acc[c][3], __builtin_bit_cast(h2, u.w));
    }
  };

  if (s >= 8) wslot(s - 8);
  __syncthreads();
  if (s < 8) rmerge(s);
  __syncthreads();
  if (s >= 4 && s < 8) wslot(s - 4);
  __syncthreads();
  if (s < 4) rmerge(s);
  __syncthreads();
  if (s == 2 || s == 3) wslot(s - 2);
  __syncthreads();
  if (s < 2) rmerge(s);
  __syncthreads();
  if (s == 1) wslot(0);
  __syncthreads();
  if (s == 0) { rmerge(0); wslot(0); }
  __syncthreads();

  // ---- distributed epilogue: thread -> (k, 4 j's), coalesced f32x4 ----
  {
    const int kr  = tid >> 3;                 // 0..63
    const int jq  = tid & 7;                  // 0..7
    const int ot5 = (kr >> 3) * 4 + (jq >> 1);
    const int oc  = kr & 7;
    const uint4 u = mrg[ot5 * 8 + (oc ^ (ot5 & 7))];
    const h2 pa = __builtin_bit_cast(h2, (jq & 1) ? u.z : u.x);
    const h2 pb = __builtin_bit_cast(h2, (jq & 1) ? u.w : u.y);
    const int k = k0 + kr, j = j0 + jq * 4;
    f32x4 o = { (float)pa[0], (float)pa[1], (float)pb[0], (float)pb[1] };
    o = __builtin_elementwise_max(o, *reinterpret_cast<const f32x4*>(&x1[k * Dk + j]));
    *reinterpret_cast<f32x4*>(&out[k * Dk + j]) = o;
  }
}

extern "C" void kernel_launch(void* const* d_in, const int* in_sizes, int n_in,
                              void* d_out, int out_size, void* d_ws, size_t ws_size,
                              hipStream_t stream) {
  const float* x0 = (const float*)d_in[0];
  const float* x1 = (const float*)d_in[1];
  const float* Cn = (const float*)d_in[2];
  const float* W  = (const float*)d_in[3];
  const float* Bm = (const float*)d_in[4];
  float* out = (float*)d_out;

  const int n = in_sizes[0] / Dk;              // 4096
  const int grid = (n / 64) * 8;               // 512 blocks
  hipLaunchKernelGGL(mp_kernel, dim3(grid), dim3(512), 0, stream,
                     x0, x1, Cn, W, Bm, out);
}

// Round 10
// 25.328 us; speedup vs baseline: 1.6092x; 1.6092x over previous
//
#include <hip/hip_runtime.h>

// out[k][j] = max( x1[k][j], max_i( W[i][j]*x0[k][i] + B[i][j] + C_norm[i][j] ) )
// N=4096, D=256, f32 in/out. pk-f16 math FORCED via inline asm v_pk_fma_f16 /
// v_pk_max_f16 with op_sel broadcast (absmax 0.031 < 0.101 validated).
//
// prep: f32->f16 streaming convert of x0, W, A=B+C into d_ws.
// main: 512 blocks x 512 thr (2 blk/CU). Tile 64k x 32j, 16-way i-split,
// per-thread 8k x 8j. X tile XOR-swizzled (store+read) -> <=2-way conflicts.
// One stage + one barrier; inner loop = 1024 pk insts, 48 ds_read_b128.

typedef _Float16 h16;
typedef h16 h2  __attribute__((ext_vector_type(2)));
typedef h16 h8v __attribute__((ext_vector_type(8)));
typedef float f32x4 __attribute__((ext_vector_type(4)));

constexpr int Dk = 256;
constexpr int NK = 4096;

// acc = pk_max(acc, pk_fma(w, broadcast_half(x2), a))
#define PK_LO(ACC, W_, X_, A_) do { h2 _t;                                      \
    asm("v_pk_fma_f16 %0, %1, %2, %3 op_sel:[0,0,0] op_sel_hi:[1,0,1]"          \
        : "=v"(_t) : "v"(W_), "v"(X_), "v"(A_));                                \
    asm("v_pk_max_f16 %0, %0, %1" : "+v"(ACC) : "v"(_t)); } while (0)
#define PK_HI(ACC, W_, X_, A_) do { h2 _t;                                      \
    asm("v_pk_fma_f16 %0, %1, %2, %3 op_sel:[0,1,0] op_sel_hi:[1,1,1]"          \
        : "=v"(_t) : "v"(W_), "v"(X_), "v"(A_));                                \
    asm("v_pk_max_f16 %0, %0, %1" : "+v"(ACC) : "v"(_t)); } while (0)

// ---------------- prep: pure streaming f32 -> f16 converts ----------------
__global__ __launch_bounds__(256)
void prep(const float* __restrict__ x0, const float* __restrict__ Cn,
          const float* __restrict__ W, const float* __restrict__ Bm,
          h16* __restrict__ x0h, h16* __restrict__ Wh, h16* __restrict__ Ah) {
  const int b = blockIdx.x, t = threadIdx.x;
  if (b < 512) {                        // x0: 1M elems, 8/thread
    const int idx = (b * 256 + t) * 8;
    const f32x4 v0 = *reinterpret_cast<const f32x4*>(&x0[idx]);
    const f32x4 v1 = *reinterpret_cast<const f32x4*>(&x0[idx + 4]);
    h8v h;
#pragma unroll
    for (int u = 0; u < 4; ++u) { h[u] = (h16)v0[u]; h[u + 4] = (h16)v1[u]; }
    *reinterpret_cast<h8v*>(&x0h[idx]) = h;
  } else {                              // W, A=B+C: 65536 elems, 8/thread
    const int idx = ((b - 512) * 256 + t) * 8;
    const f32x4 w0 = *reinterpret_cast<const f32x4*>(&W[idx]);
    const f32x4 w1 = *reinterpret_cast<const f32x4*>(&W[idx + 4]);
    const f32x4 b0 = *reinterpret_cast<const f32x4*>(&Bm[idx]);
    const f32x4 b1 = *reinterpret_cast<const f32x4*>(&Bm[idx + 4]);
    const f32x4 c0 = *reinterpret_cast<const f32x4*>(&Cn[idx]);
    const f32x4 c1 = *reinterpret_cast<const f32x4*>(&Cn[idx + 4]);
    const f32x4 a0 = b0 + c0, a1 = b1 + c1;
    h8v hw, ha;
#pragma unroll
    for (int u = 0; u < 4; ++u) {
      hw[u] = (h16)w0[u]; hw[u + 4] = (h16)w1[u];
      ha[u] = (h16)a0[u]; ha[u + 4] = (h16)a1[u];
    }
    *reinterpret_cast<h8v*>(&Wh[idx]) = hw;
    *reinterpret_cast<h8v*>(&Ah[idx]) = ha;
  }
}

// ---------------- main ----------------
__global__ __launch_bounds__(512, 4)
void mp_main(const h16* __restrict__ x0h, const h16* __restrict__ Wh,
             const h16* __restrict__ Ah, const float* __restrict__ x1,
             float* __restrict__ out) {
  __shared__ __align__(16) h16 smem[32768];   // 64 KB
  h16* Xl = smem;            // [64 k][256 i], col ^= (k>>3)*8   32KB
  h16* Wl = smem + 16384;    // [256 i][32 j]                    16KB
  h16* Al = smem + 24576;    // [256 i][32 j]                    16KB

  const int tid = threadIdx.x;
  const int s  = tid >> 5;         // i-slice 0..15 (16 i's each)
  const int t5 = tid & 31;
  const int tk = t5 >> 2;          // k-group 0..7 (8 k's)
  const int tj = t5 & 3;           // j-group 0..3 (8 j's)
  const int k0 = (int)(blockIdx.x >> 3) * 64;
  const int j0 = (int)(blockIdx.x & 7) * 32;

  // ---- stage X tile (swizzled), W/A tiles (plain f16 copies) ----
#pragma unroll
  for (int c = 0; c < 4; ++c) {
    const int idx = c * 512 + tid;          // 2048 chunks
    const int row = idx >> 5;               // k-row 0..63
    const int ic8 = (idx & 31) * 8;
    const h8v v = *reinterpret_cast<const h8v*>(&x0h[(k0 + row) * Dk + ic8]);
    *reinterpret_cast<h8v*>(&Xl[row * 256 + (ic8 ^ ((row >> 3) * 8))]) = v;
  }
#pragma unroll
  for (int c = 0; c < 2; ++c) {
    const int idx = c * 512 + tid;          // 1024 chunks
    const int row = idx >> 2;               // i 0..255
    const int jc8 = (idx & 3) * 8;
    *reinterpret_cast<h8v*>(&Wl[row * 32 + jc8]) =
        *reinterpret_cast<const h8v*>(&Wh[row * Dk + j0 + jc8]);
    *reinterpret_cast<h8v*>(&Al[row * 32 + jc8]) =
        *reinterpret_cast<const h8v*>(&Ah[row * Dk + j0 + jc8]);
  }
  __syncthreads();

  h2 acc[8][4];
#pragma unroll
  for (int kk = 0; kk < 8; ++kk)
#pragma unroll
    for (int p = 0; p < 4; ++p)
      acc[kk][p] = h2{(h16)(-60000.0f), (h16)(-60000.0f)};

  // xk extraction: dword (U>>1) of xr[kk]; op_sel picks half U&1.
#define USTEP(U, SEL) {                                                         \
    const int ii = i0 + (U);                                                    \
    const h8v wv = *reinterpret_cast<const h8v*>(&Wl[ii * 32 + tj * 8]);        \
    const h8v av = *reinterpret_cast<const h8v*>(&Al[ii * 32 + tj * 8]);        \
    const h2 w0 = __builtin_shufflevector(wv, wv, 0, 1);                        \
    const h2 w1 = __builtin_shufflevector(wv, wv, 2, 3);                        \
    const h2 w2 = __builtin_shufflevector(wv, wv, 4, 5);                        \
    const h2 w3 = __builtin_shufflevector(wv, wv, 6, 7);                        \
    const h2 a0 = __builtin_shufflevector(av, av, 0, 1);                        \
    const h2 a1 = __builtin_shufflevector(av, av, 2, 3);                        \
    const h2 a2 = __builtin_shufflevector(av, av, 4, 5);                        \
    const h2 a3 = __builtin_shufflevector(av, av, 6, 7);                        \
    _Pragma("unroll")                                                           \
    for (int kk = 0; kk < 8; ++kk) {                                            \
      const h2 xk = __builtin_shufflevector(xr[kk], xr[kk],                     \
                                            ((U) >> 1) * 2, ((U) >> 1) * 2 + 1);\
      SEL(acc[kk][0], w0, xk, a0);                                              \
      SEL(acc[kk][1], w1, xk, a1);                                              \
      SEL(acc[kk][2], w2, xk, a2);                                              \
      SEL(acc[kk][3], w3, xk, a3);                                              \
    }                                                                           \
  }

#pragma unroll
  for (int hh = 0; hh < 2; ++hh) {
    const int i0 = s * 16 + hh * 8;
    h8v xr[8];
#pragma unroll
    for (int kk = 0; kk < 8; ++kk) {
      const int row = tk * 8 + kk;
      xr[kk] = *reinterpret_cast<const h8v*>(
          &Xl[row * 256 + (i0 ^ ((row >> 3) * 8))]);
    }
    USTEP(0, PK_LO) USTEP(1, PK_HI) USTEP(2, PK_LO) USTEP(3, PK_HI)
    USTEP(4, PK_LO) USTEP(5, PK_HI) USTEP(6, PK_LO) USTEP(7, PK_HI)
  }
#undef USTEP

  __syncthreads();   // LDS reuse as merge scratch

  // ---- tree merge: 16 i-slices -> 1 ----
  uint4* mrg = reinterpret_cast<uint4*>(smem);
  auto wslot = [&](int slot) {
#pragma unroll
    for (int c = 0; c < 8; ++c) {
      uint4 u;
      u.x = __builtin_bit_cast(unsigned int, acc[c][0]);
      u.y = __builtin_bit_cast(unsigned int, acc[c][1]);
      u.z = __builtin_bit_cast(unsigned int, acc[c][2]);
      u.w = __builtin_bit_cast(unsigned int, acc[c][3]);
      mrg[(slot * 32 + t5) * 8 + (c ^ (t5 & 7))] = u;
    }
  };
  auto rmerge = [&](int slot) {
#pragma unroll
    for (int c = 0; c < 8; ++c) {
      const uint4 u = mrg[(slot * 32 + t5) * 8 + (c ^ (t5 & 7))];
      h2 v0 = __builtin_bit_cast(h2, u.x), v1 = __builtin_bit_cast(h2, u.y);
      h2 v2 = __builtin_bit_cast(h2, u.z), v3 = __builtin_bit_cast(h2, u.w);
      asm("v_pk_max_f16 %0, %0, %1" : "+v"(acc[c][0]) : "v"(v0));
      asm("v_pk_max_f16 %0, %0, %1" : "+v"(acc[c][1]) : "v"(v1));
      asm("v_pk_max_f16 %0, %0, %1" : "+v"(acc[c][2]) : "v"(v2));
      asm("v_pk_max_f16 %0, %0, %1" : "+v"(acc[c][3]) : "v"(v3));
    }
  };

  if (s >= 8) wslot(s - 8);
  __syncthreads();
  if (s < 8) rmerge(s);
  __syncthreads();
  if (s >= 4 && s < 8) wslot(s - 4);
  __syncthreads();
  if (s < 4) rmerge(s);
  __syncthreads();
  if (s == 2 || s == 3) wslot(s - 2);
  __syncthreads();
  if (s < 2) rmerge(s);
  __syncthreads();
  if (s == 1) wslot(0);
  __syncthreads();
  if (s == 0) { rmerge(0); wslot(0); }
  __syncthreads();

  // ---- distributed epilogue: thread -> (k, 4 j's), coalesced f32x4 ----
  {
    const int kr  = tid >> 3;                 // 0..63
    const int jq  = tid & 7;                  // 0..7
    const int ot5 = (kr >> 3) * 4 + (jq >> 1);
    const int oc  = kr & 7;
    const uint4 u = mrg[ot5 * 8 + (oc ^ (ot5 & 7))];
    const h2 pa = __builtin_bit_cast(h2, (jq & 1) ? u.z : u.x);
    const h2 pb = __builtin_bit_cast(h2, (jq & 1) ? u.w : u.y);
    const int k = k0 + kr, j = j0 + jq * 4;
    f32x4 o = { (float)pa[0], (float)pa[1], (float)pb[0], (float)pb[1] };
    o = __builtin_elementwise_max(o, *reinterpret_cast<const f32x4*>(&x1[k * Dk + j]));
    *reinterpret_cast<f32x4*>(&out[k * Dk + j]) = o;
  }
}

extern "C" void kernel_launch(void* const* d_in, const int* in_sizes, int n_in,
                              void* d_out, int out_size, void* d_ws, size_t ws_size,
                              hipStream_t stream) {
  const float* x0 = (const float*)d_in[0];
  const float* x1 = (const float*)d_in[1];
  const float* Cn = (const float*)d_in[2];
  const float* W  = (const float*)d_in[3];
  const float* Bm = (const float*)d_in[4];
  float* out = (float*)d_out;

  h16* x0h = (h16*)d_ws;                                          // 2 MB
  h16* Wh  = (h16*)((char*)d_ws + (size_t)NK * Dk * 2);           // 128 KB
  h16* Ah  = (h16*)((char*)d_ws + (size_t)NK * Dk * 2 + Dk * Dk * 2);

  hipLaunchKernelGGL(prep, dim3(512 + 32), dim3(256), 0, stream,
                     x0, Cn, W, Bm, x0h, Wh, Ah);
  hipLaunchKernelGGL(mp_main, dim3(512), dim3(512), 0, stream,
                     x0h, Wh, Ah, x1, out);
}

// Round 11
// 23.617 us; speedup vs baseline: 1.7258x; 1.0725x over previous
//
#include <hip/hip_runtime.h>

// out[k][j] = max( x1[k][j], max_i( W[i][j]*x0[k][i] + B[i][j] + C_norm[i][j] ) )
// N=4096, D=256, f32 in/out. pk-f16 math via builtins (absmax 0.031 < 0.101).
//
// R11: single kernel. 512 blocks x 512 thr (2 blk/CU, 4 waves/SIMD), tile
// 64k x 32j. LDS 64KB: X[64][256] swizzled + W/A[256][32]. Staging: X and
// W/A-half0 up front; W/A-half1 global->reg issued BEFORE phase-0 compute
// (latency hidden under ~8k cyc of pk math), ds_write after. Per-thread
// 8k x 8j x 16i in two i-phases (i = p*128 + s*8). pk-f16 is HALF-RATE on
// gfx950 (R9 counter evidence) -> VALU floor ~6.8us; this round removes
// prep/launch/stage overhead. x1 prefetched before merge tree.

typedef _Float16 h16;
typedef h16 h2  __attribute__((ext_vector_type(2)));
typedef h16 h8v __attribute__((ext_vector_type(8)));
typedef float f32x4 __attribute__((ext_vector_type(4)));

constexpr int Dk = 256;

__global__ __launch_bounds__(512, 4)
void mp_kernel(const float* __restrict__ x0, const float* __restrict__ x1,
               const float* __restrict__ Cn, const float* __restrict__ W,
               const float* __restrict__ Bm, float* __restrict__ out) {
  __shared__ __align__(16) h16 smem[32768];   // 64 KB
  h16* Xl = smem;            // [64 k][256 i], col ^= (k>>3)*8   32KB
  h16* Wl = smem + 16384;    // [256 i][32 j]                    16KB
  h16* Al = smem + 24576;    // [256 i][32 j]                    16KB

  const int tid = threadIdx.x;
  const int s  = tid >> 5;         // i-slice 0..15 (8 i's per phase)
  const int t5 = tid & 31;
  const int tk = t5 >> 2;          // k-group 0..7 (8 k's)
  const int tj = t5 & 3;           // j-group 0..3 (8 j's)
  const int k0 = (int)(blockIdx.x >> 3) * 64;
  const int j0 = (int)(blockIdx.x & 7) * 32;

  // ---- stage X tile (64k x 256i f32 -> f16, swizzled store) ----
#pragma unroll
  for (int c = 0; c < 4; ++c) {
    const int idx = c * 512 + tid;          // 2048 chunks
    const int row = idx >> 5;               // k-row 0..63
    const int ic8 = (idx & 31) * 8;
    const f32x4 v0 = *reinterpret_cast<const f32x4*>(&x0[(k0 + row) * Dk + ic8]);
    const f32x4 v1 = *reinterpret_cast<const f32x4*>(&x0[(k0 + row) * Dk + ic8 + 4]);
    h8v h;
#pragma unroll
    for (int u = 0; u < 4; ++u) { h[u] = (h16)v0[u]; h[u + 4] = (h16)v1[u]; }
    *reinterpret_cast<h8v*>(&Xl[row * 256 + (ic8 ^ ((row >> 3) * 8))]) = h;
  }
  // ---- stage W/A half 0 (i = 0..127) ----
  {
    const int row = tid >> 2;               // i 0..127
    const int jc8 = (tid & 3) * 8;
    const int g = row * Dk + j0 + jc8;
    const f32x4 w0 = *reinterpret_cast<const f32x4*>(&W[g]);
    const f32x4 w1 = *reinterpret_cast<const f32x4*>(&W[g + 4]);
    const f32x4 b0 = *reinterpret_cast<const f32x4*>(&Bm[g]);
    const f32x4 b1 = *reinterpret_cast<const f32x4*>(&Bm[g + 4]);
    const f32x4 c0 = *reinterpret_cast<const f32x4*>(&Cn[g]);
    const f32x4 c1 = *reinterpret_cast<const f32x4*>(&Cn[g + 4]);
    const f32x4 a0 = b0 + c0, a1 = b1 + c1;
    h8v hw, ha;
#pragma unroll
    for (int u = 0; u < 4; ++u) {
      hw[u] = (h16)w0[u]; hw[u + 4] = (h16)w1[u];
      ha[u] = (h16)a0[u]; ha[u + 4] = (h16)a1[u];
    }
    *reinterpret_cast<h8v*>(&Wl[row * 32 + jc8]) = hw;
    *reinterpret_cast<h8v*>(&Al[row * 32 + jc8]) = ha;
  }
  __syncthreads();

  // ---- issue W/A half-1 global loads NOW (land during phase-0 compute) ----
  const int prow = 128 + (tid >> 2);
  const int pjc8 = (tid & 3) * 8;
  const int pg = prow * Dk + j0 + pjc8;
  const f32x4 pw0 = *reinterpret_cast<const f32x4*>(&W[pg]);
  const f32x4 pw1 = *reinterpret_cast<const f32x4*>(&W[pg + 4]);
  const f32x4 pb0 = *reinterpret_cast<const f32x4*>(&Bm[pg]);
  const f32x4 pb1 = *reinterpret_cast<const f32x4*>(&Bm[pg + 4]);
  const f32x4 pc0 = *reinterpret_cast<const f32x4*>(&Cn[pg]);
  const f32x4 pc1 = *reinterpret_cast<const f32x4*>(&Cn[pg + 4]);

  h2 acc[8][4];
#pragma unroll
  for (int kk = 0; kk < 8; ++kk)
#pragma unroll
    for (int p = 0; p < 4; ++p)
      acc[kk][p] = h2{(h16)(-60000.0f), (h16)(-60000.0f)};

#define USTEP(U) {                                                              \
    const int ii = i0 + (U);                                                    \
    const h8v wv = *reinterpret_cast<const h8v*>(&Wl[ii * 32 + tj * 8]);        \
    const h8v av = *reinterpret_cast<const h8v*>(&Al[ii * 32 + tj * 8]);        \
    const h2 w0 = __builtin_shufflevector(wv, wv, 0, 1);                        \
    const h2 w1 = __builtin_shufflevector(wv, wv, 2, 3);                        \
    const h2 w2 = __builtin_shufflevector(wv, wv, 4, 5);                        \
    const h2 w3 = __builtin_shufflevector(wv, wv, 6, 7);                        \
    const h2 a0 = __builtin_shufflevector(av, av, 0, 1);                        \
    const h2 a1 = __builtin_shufflevector(av, av, 2, 3);                        \
    const h2 a2 = __builtin_shufflevector(av, av, 4, 5);                        \
    const h2 a3 = __builtin_shufflevector(av, av, 6, 7);                        \
    _Pragma("unroll")                                                           \
    for (int kk = 0; kk < 8; ++kk) {                                            \
      const h2 xb = __builtin_shufflevector(xr[kk], xr[kk], (U), (U));          \
      acc[kk][0] = __builtin_elementwise_max(acc[kk][0], __builtin_elementwise_fma(w0, xb, a0)); \
      acc[kk][1] = __builtin_elementwise_max(acc[kk][1], __builtin_elementwise_fma(w1, xb, a1)); \
      acc[kk][2] = __builtin_elementwise_max(acc[kk][2], __builtin_elementwise_fma(w2, xb, a2)); \
      acc[kk][3] = __builtin_elementwise_max(acc[kk][3], __builtin_elementwise_fma(w3, xb, a3)); \
    }                                                                           \
  }

  // ---- phase 0: i = s*8 .. s*8+7 (half 0 only) ----
  {
    const int i0 = s * 8;
    h8v xr[8];
#pragma unroll
    for (int kk = 0; kk < 8; ++kk) {
      const int row = tk * 8 + kk;
      xr[kk] = *reinterpret_cast<const h8v*>(
          &Xl[row * 256 + (i0 ^ ((row >> 3) * 8))]);
    }
    USTEP(0) USTEP(1) USTEP(2) USTEP(3) USTEP(4) USTEP(5) USTEP(6) USTEP(7)
  }

  // ---- write W/A half 1 (loads have landed under phase-0 compute) ----
  {
    const f32x4 pa0 = pb0 + pc0, pa1 = pb1 + pc1;
    h8v hw, ha;
#pragma unroll
    for (int u = 0; u < 4; ++u) {
      hw[u] = (h16)pw0[u]; hw[u + 4] = (h16)pw1[u];
      ha[u] = (h16)pa0[u]; ha[u + 4] = (h16)pa1[u];
    }
    *reinterpret_cast<h8v*>(&Wl[prow * 32 + pjc8]) = hw;
    *reinterpret_cast<h8v*>(&Al[prow * 32 + pjc8]) = ha;
  }
  __syncthreads();

  // ---- phase 1: i = 128 + s*8 .. +7 ----
  {
    const int i0 = 128 + s * 8;
    h8v xr[8];
#pragma unroll
    for (int kk = 0; kk < 8; ++kk) {
      const int row = tk * 8 + kk;
      xr[kk] = *reinterpret_cast<const h8v*>(
          &Xl[row * 256 + (i0 ^ ((row >> 3) * 8))]);
    }
    USTEP(0) USTEP(1) USTEP(2) USTEP(3) USTEP(4) USTEP(5) USTEP(6) USTEP(7)
  }
#undef USTEP

  __syncthreads();   // LDS reuse as merge scratch

  // ---- prefetch x1 for the epilogue (hides under merge tree) ----
  const int kr  = tid >> 3;                 // 0..63
  const int jq  = tid & 7;                  // 0..7
  const int ek  = k0 + kr;
  const int ej  = j0 + jq * 4;
  const f32x4 x1v = *reinterpret_cast<const f32x4*>(&x1[ek * Dk + ej]);

  // ---- tree merge: 16 i-slices -> 1 ----
  uint4* mrg = reinterpret_cast<uint4*>(smem);
  auto wslot = [&](int slot) {
#pragma unroll
    for (int c = 0; c < 8; ++c) {
      uint4 u;
      u.x = __builtin_bit_cast(unsigned int, acc[c][0]);
      u.y = __builtin_bit_cast(unsigned int, acc[c][1]);
      u.z = __builtin_bit_cast(unsigned int, acc[c][2]);
      u.w = __builtin_bit_cast(unsigned int, acc[c][3]);
      mrg[(slot * 32 + t5) * 8 + (c ^ (t5 & 7))] = u;
    }
  };
  auto rmerge = [&](int slot) {
#pragma unroll
    for (int c = 0; c < 8; ++c) {
      const uint4 u = mrg[(slot * 32 + t5) * 8 + (c ^ (t5 & 7))];
      acc[c][0] = __builtin_elementwise_max(acc[c][0], __builtin_bit_cast(h2, u.x));
      acc[c][1] = __builtin_elementwise_max(acc[c][1], __builtin_bit_cast(h2, u.y));
      acc[c][2] = __builtin_elementwise_max(acc[c][2], __builtin_bit_cast(h2, u.z));
      acc[c][3] = __builtin_elementwise_max(acc[c][3], __builtin_bit_cast(h2, u.w));
    }
  };

  if (s >= 8) wslot(s - 8);
  __syncthreads();
  if (s < 8) rmerge(s);
  __syncthreads();
  if (s >= 4 && s < 8) wslot(s - 4);
  __syncthreads();
  if (s < 4) rmerge(s);
  __syncthreads();
  if (s == 2 || s == 3) wslot(s - 2);
  __syncthreads();
  if (s < 2) rmerge(s);
  __syncthreads();
  if (s == 1) wslot(0);
  __syncthreads();
  if (s == 0) { rmerge(0); wslot(0); }
  __syncthreads();

  // ---- distributed epilogue: thread -> (k, 4 j's), coalesced f32x4 ----
  {
    const int ot5 = (kr >> 3) * 4 + (jq >> 1);
    const int oc  = kr & 7;
    const uint4 u = mrg[ot5 * 8 + (oc ^ (ot5 & 7))];
    const h2 pa = __builtin_bit_cast(h2, (jq & 1) ? u.z : u.x);
    const h2 pb = __builtin_bit_cast(h2, (jq & 1) ? u.w : u.y);
    f32x4 o = { (float)pa[0], (float)pa[1], (float)pb[0], (float)pb[1] };
    o = __builtin_elementwise_max(o, x1v);
    *reinterpret_cast<f32x4*>(&out[ek * Dk + ej]) = o;
  }
}

extern "C" void kernel_launch(void* const* d_in, const int* in_sizes, int n_in,
                              void* d_out, int out_size, void* d_ws, size_t ws_size,
                              hipStream_t stream) {
  const float* x0 = (const float*)d_in[0];
  const float* x1 = (const float*)d_in[1];
  const float* Cn = (const float*)d_in[2];
  const float* W  = (const float*)d_in[3];
  const float* Bm = (const float*)d_in[4];
  float* out = (float*)d_out;

  const int n = in_sizes[0] / Dk;              // 4096
  const int grid = (n / 64) * 8;               // 512 blocks
  hipLaunchKernelGGL(mp_kernel, dim3(grid), dim3(512), 0, stream,
                     x0, x1, Cn, W, Bm, out);
}